// Round 10
// baseline (199.470 us; speedup 1.0000x reference)
//
#include <hip/hip_runtime.h>

// CNN_36644660970295: 16 steps of [wrap-pad, conv3x3 1->2ch, +b1, tanh,
// conv1x1 2->1ch, +b2, relu] on B=32, 512x512 fp32.
// Round 10: 16 bands x 32 rows (5 rows/wave), single-parity 32KB exchange LDS
// (2 barriers/step), weights forced to SGPR via readfirstlane, lazy below-read.

#define NN 512
#define NTHR 512
#define ROWS 5                  // rows per wave (32 valid + 8 halo per WG)
#define VALID 32
#define TWO_LOG2E 2.8853900817779268f   // 2*log2(e)

typedef float f4 __attribute__((ext_vector_type(4)));

__device__ __forceinline__ float permf(int addr, float v) {
    return __builtin_bit_cast(float,
        __builtin_amdgcn_ds_bpermute(addr, __builtin_bit_cast(int, v)));
}
__device__ __forceinline__ float rfl(float x) {   // force to SGPR
    return __builtin_bit_cast(float,
        __builtin_amdgcn_readfirstlane(__builtin_bit_cast(int, x)));
}

// epilogue: y = relu(V0/(e0+1) + V1/(e1+1) + C2), algebraically:
// num = V0*e1 + V1*e0 + (V0+V1);  m = e0*e1 + e0 + e1 + 1;  y = num/m + C2
#define PXOUT(A0, A1)                                                        \
    ({  float e0_ = __builtin_amdgcn_exp2f(A0);                              \
        float e1_ = __builtin_amdgcn_exp2f(A1);                              \
        float m_  = fmaf(e0_, e1_, (e0_ + e1_) + 1.0f);                      \
        float nm_ = fmaf(V0, e1_, fmaf(V1, e0_, V01));                       \
        fmaxf(fmaf(nm_, __builtin_amdgcn_rcpf(m_), C2), 0.0f); })

__global__ __launch_bounds__(NTHR, 2) void fused4(
    const float* __restrict__ in, float* __restrict__ out,
    const float* __restrict__ w1p, const float* __restrict__ b1p,
    const float* __restrict__ w2p, const float* __restrict__ b2p)
{
    __shared__ float xch[8 * 2 * NN];       // [wave][top/bot][col] = 32 KB

    const int tid  = threadIdx.x;
    const int wv   = tid >> 6;              // wave 0..7
    const int l    = tid & 63;              // lane
    const int wg   = blockIdx.x;
    const int band = wg & 15;               // 16 bands of 32 rows
    const int b    = wg >> 4;               // image
    const float* img = in + (size_t)b * (NN * NN);
    const int G  = band * VALID;            // first valid global row of band
    const int c0 = l << 3;                  // col base (8 cols per lane)

    // ---- stage 5 rows/wave from global (true wrap) into registers ----
    f4 xu[ROWS], xv[ROWS];
    #pragma unroll
    for (int r = 0; r < ROWS; ++r) {
        int g = (G - 4 + ROWS * wv + r) & (NN - 1);
        const float* p = img + g * NN + c0;
        xu[r] = *reinterpret_cast<const f4*>(p);
        xv[r] = *reinterpret_cast<const f4*>(p + 4);
    }

    // ---- weights: uniform -> SGPR (readfirstlane), pre-scaled for exp2 ----
    float W[2][3][3];
    #pragma unroll
    for (int ch = 0; ch < 2; ++ch)
        #pragma unroll
        for (int r = 0; r < 3; ++r)
            #pragma unroll
            for (int q = 0; q < 3; ++q)
                W[ch][r][q] = rfl(w1p[ch * 9 + r * 3 + q] * TWO_LOG2E);
    const float B10 = rfl(b1p[0] * TWO_LOG2E), B11 = rfl(b1p[1] * TWO_LOG2E);
    const float V0  = rfl(-2.0f * w2p[0]),     V1  = rfl(-2.0f * w2p[1]);
    const float V01 = rfl(V0 + V1);
    const float C2  = rfl(w2p[0] + w2p[1] + b2p[0]);

    const int aU = ((l + 63) & 63) << 2;    // bpermute: lane-1 (wrap)
    const int aD = ((l + 1)  & 63) << 2;    // bpermute: lane+1 (wrap)

    const int topo = (wv * 2 + 0) * NN + c0;
    const int boto = (wv * 2 + 1) * NN + c0;
    const int abvo = (((wv + 7) & 7) * 2 + 1) * NN + c0;  // above-neighbor bottom
    const int belo = (((wv + 1) & 7) * 2 + 0) * NN + c0;  // below-neighbor top

    // ---- 4 fused steps: post -> bar -> read+compute -> bar ----
    #pragma unroll 1
    for (int s = 0; s < 4; ++s) {
        *reinterpret_cast<f4*>(xch + topo)     = xu[0];
        *reinterpret_cast<f4*>(xch + topo + 4) = xv[0];
        *reinterpret_cast<f4*>(xch + boto)     = xu[ROWS - 1];
        *reinterpret_cast<f4*>(xch + boto + 4) = xv[ROWS - 1];
        __syncthreads();                     // posts visible

        f4 pu = *reinterpret_cast<const f4*>(xch + abvo);
        f4 pv = *reinterpret_cast<const f4*>(xch + abvo + 4);

        #pragma unroll
        for (int r = 0; r < ROWS; ++r) {
            f4 cu = xu[r], cv = xv[r];
            f4 nu, nv;
            if (r == ROWS - 1) {
                nu = *reinterpret_cast<const f4*>(xch + belo);
                nv = *reinterpret_cast<const f4*>(xch + belo + 4);
            } else {
                nu = xu[r + 1]; nv = xv[r + 1];
            }

            f4 a0U, a0V, a1U, a1V;
            {   // channel 0
                f4 s0u = W[0][0][0]*pu + W[0][1][0]*cu + W[0][2][0]*nu;
                f4 s0v = W[0][0][0]*pv + W[0][1][0]*cv + W[0][2][0]*nv;
                f4 s1u = W[0][0][1]*pu + W[0][1][1]*cu + W[0][2][1]*nu + B10;
                f4 s1v = W[0][0][1]*pv + W[0][1][1]*cv + W[0][2][1]*nv + B10;
                f4 s2u = W[0][0][2]*pu + W[0][1][2]*cu + W[0][2][2]*nu;
                f4 s2v = W[0][0][2]*pv + W[0][1][2]*cv + W[0][2][2]*nv;
                float Lm = permf(aU, s0v.w);   // s0[-1] from left lane (wrap)
                float Rp = permf(aD, s2u.x);   // s2[8] from right lane (wrap)
                a0U.x = s1u.x + Lm    + s2u.y;
                a0U.y = s1u.y + s0u.x + s2u.z;
                a0U.z = s1u.z + s0u.y + s2u.w;
                a0U.w = s1u.w + s0u.z + s2v.x;
                a0V.x = s1v.x + s0u.w + s2v.y;
                a0V.y = s1v.y + s0v.x + s2v.z;
                a0V.z = s1v.z + s0v.y + s2v.w;
                a0V.w = s1v.w + s0v.z + Rp;
            }
            {   // channel 1
                f4 s0u = W[1][0][0]*pu + W[1][1][0]*cu + W[1][2][0]*nu;
                f4 s0v = W[1][0][0]*pv + W[1][1][0]*cv + W[1][2][0]*nv;
                f4 s1u = W[1][0][1]*pu + W[1][1][1]*cu + W[1][2][1]*nu + B11;
                f4 s1v = W[1][0][1]*pv + W[1][1][1]*cv + W[1][2][1]*nv + B11;
                f4 s2u = W[1][0][2]*pu + W[1][1][2]*cu + W[1][2][2]*nu;
                f4 s2v = W[1][0][2]*pv + W[1][1][2]*cv + W[1][2][2]*nv;
                float Lm = permf(aU, s0v.w);
                float Rp = permf(aD, s2u.x);
                a1U.x = s1u.x + Lm    + s2u.y;
                a1U.y = s1u.y + s0u.x + s2u.z;
                a1U.z = s1u.z + s0u.y + s2u.w;
                a1U.w = s1u.w + s0u.z + s2v.x;
                a1V.x = s1v.x + s0u.w + s2v.y;
                a1V.y = s1v.y + s0v.x + s2v.z;
                a1V.z = s1v.z + s0v.y + s2v.w;
                a1V.w = s1v.w + s0v.z + Rp;
            }
            f4 ru, rv;
            ru.x = PXOUT(a0U.x, a1U.x);
            ru.y = PXOUT(a0U.y, a1U.y);
            ru.z = PXOUT(a0U.z, a1U.z);
            ru.w = PXOUT(a0U.w, a1U.w);
            rv.x = PXOUT(a0V.x, a1V.x);
            rv.y = PXOUT(a0V.y, a1V.y);
            rv.z = PXOUT(a0V.z, a1V.z);
            rv.w = PXOUT(a0V.w, a1V.w);
            xu[r] = ru; xv[r] = rv;
            pu = cu; pv = cv;                // old row becomes prev
        }
        __syncthreads();                     // all reads done before next post
    }

    // ---- writeout valid band rows [4..35] ----
    float* og = out + (size_t)b * (NN * NN);
    #pragma unroll
    for (int r = 0; r < ROWS; ++r) {
        int rb = ROWS * wv + r;
        if (rb >= 4 && rb <= VALID + 3) {
            float* p = og + (size_t)(G + rb - 4) * NN + c0;
            *reinterpret_cast<f4*>(p)     = xu[r];
            *reinterpret_cast<f4*>(p + 4) = xv[r];
        }
    }
}

extern "C" void kernel_launch(void* const* d_in, const int* in_sizes, int n_in,
                              void* d_out, int out_size, void* d_ws, size_t ws_size,
                              hipStream_t stream) {
    const float* x  = (const float*)d_in[0];
    const float* w1 = (const float*)d_in[1];
    const float* b1 = (const float*)d_in[2];
    const float* w2 = (const float*)d_in[3];
    const float* b2 = (const float*)d_in[4];

    float* A = (float*)d_ws;    // ping
    float* B = (float*)d_out;   // pong (final group lands here)

    dim3 grid(32 * 16), block(NTHR);   // 512 WGs -> 2 per CU

    fused4<<<grid, block, 0, stream>>>(x, A, w1, b1, w2, b2);
    fused4<<<grid, block, 0, stream>>>(A, B, w1, b1, w2, b2);
    fused4<<<grid, block, 0, stream>>>(B, A, w1, b1, w2, b2);
    fused4<<<grid, block, 0, stream>>>(A, B, w1, b1, w2, b2);
}